// Round 27
// baseline (371.692 us; speedup 1.0000x reference)
//
#include <hip/hip_runtime.h>

#define NB   32
#define C    64
#define T    512
#define V    25
#define KP   3
#define CO   64
#define H    4
#define BN_EPS 1e-5f
#define LN_EPS 1e-6f

typedef float f32x4 __attribute__((ext_vector_type(4)));
typedef float f32x16 __attribute__((ext_vector_type(16)));
typedef short bf16x8 __attribute__((ext_vector_type(8)));
typedef unsigned short u16;
typedef unsigned int u32;
typedef u32 u32x2 __attribute__((ext_vector_type(2)));
#define MFMA(a,b,c)   __builtin_amdgcn_mfma_f32_16x16x32_bf16((a),(b),(c),0,0,0)
#define MFMA32(a,b,c) __builtin_amdgcn_mfma_f32_32x32x16_bf16((a),(b),(c),0,0,0)

__device__ __forceinline__ u16 f2bf(float x) {          // prep-side (cold)
    union { float f; unsigned u; } v; v.f = x;
    unsigned r = (v.u + 0x7FFFu + ((v.u >> 16) & 1u)) >> 16;
    return (u16)r;
}
__device__ __forceinline__ float bf2f(u16 h) {
    union { unsigned u; float f; } v; v.u = ((unsigned)h) << 16;
    return v.f;
}
// HW packed convert (gfx950, RNE; guide T12 recipe, HW-verified m214v22)
__device__ __forceinline__ u32 cvtpk(float lo, float hi) {
    u32 r;
    asm("v_cvt_pk_bf16_f32 %0, %1, %2" : "=v"(r) : "v"(lo), "v"(hi));
    return r;
}
__device__ __forceinline__ u16 f2bf1(float x) { return (u16)cvtpk(x, x); }
__device__ __forceinline__ u32x2 pack4(const f32x4& a) {
    u32x2 p;
    p[0] = cvtpk(a[0], a[1]);
    p[1] = cvtpk(a[2], a[3]);
    return p;
}

#define WOFF 52428800ull

// prep R20-validated: weights + BN affine constants
__global__ __launch_bounds__(256) void prep_kernel(
    const float* __restrict__ A, const float* __restrict__ pconv_w,
    const float* __restrict__ pconv_b,
    const float* __restrict__ wq, const float* __restrict__ wk,
    const float* __restrict__ wv, const float* __restrict__ fc_w,
    const float* __restrict__ tconv_w, const float* __restrict__ tconv_b,
    const float* __restrict__ ln_g, const float* __restrict__ ln_b,
    const float* __restrict__ bn1_g, const float* __restrict__ bn1_b,
    const float* __restrict__ bn1_m, const float* __restrict__ bn1_v,
    const float* __restrict__ bn2_g, const float* __restrict__ bn2_b,
    const float* __restrict__ bn2_m, const float* __restrict__ bn2_v,
    const float* __restrict__ bn3_g, const float* __restrict__ bn3_b,
    const float* __restrict__ bn3_m, const float* __restrict__ bn3_v,
    u16* __restrict__ akt, u16* __restrict__ wp2,
    u16* __restrict__ wqt, u16* __restrict__ wkt, u16* __restrict__ wvt,
    u16* __restrict__ fct, float* __restrict__ bagg, u16* __restrict__ wtc,
    float* __restrict__ uvec, float* __restrict__ w0vec,
    float* __restrict__ bnc)
{
    const int stride = gridDim.x * 256;
    for (int i = blockIdx.x * 256 + threadIdx.x; i < 71296; i += stride) {
        if (i < 3840) {                       // AkT
            int k = i / 1280, r = i - k * 1280, w = r / 40, v = r - w * 40;
            float val = (w < V && v < V) ? A[k * V * V + v * V + w] : 0.f;
            akt[i] = f2bf(val);
        } else if (i < 16128) {               // Wp2
            int i2 = i - 3840;
            int c = i2 / 192, kk = i2 - c * 192, k = kk / 64, ci = kk - k * 64;
            wp2[i2] = f2bf(pconv_w[(k * 64 + c) * 64 + ci]);
        } else if (i < 20224) {               // WqT (ln_g-scaled)
            int i2 = i - 16128; int j = i2 / 64, c = i2 - j * 64;
            wqt[i2] = f2bf(wq[c * 64 + j] * ln_g[c]);
        } else if (i < 24320) {               // WkT
            int i2 = i - 20224; int j = i2 / 64, c = i2 - j * 64;
            wkt[i2] = f2bf(wk[c * 64 + j]);
        } else if (i < 28416) {               // WvT
            int i2 = i - 24320; int j = i2 / 64, c = i2 - j * 64;
            wvt[i2] = f2bf(wv[c * 64 + j]);
        } else if (i < 32512) {               // FcT
            int i2 = i - 28416; int c = i2 / 64, d = i2 - c * 64;
            fct[i2] = f2bf(fc_w[d * 64 + c]);
        } else if (i < 34112) {               // bias_agg
            int i2 = i - 32512; int c = i2 / 25, w = i2 - c * 25;
            float s = 0.f;
            for (int k = 0; k < KP; ++k) {
                float cs = 0.f;
                for (int v = 0; v < V; ++v) cs += A[k * V * V + v * V + w];
                s += pconv_b[k * 64 + c] * cs;
            }
            bagg[i2] = s;
        } else if (i < 70976) {               // Wtc
            int i2 = i - 34112;
            int co = i2 / 576, rem = i2 - co * 576, dt = rem / 64, ci = rem - dt * 64;
            wtc[i2] = f2bf(tconv_w[(co * 64 + ci) * 9 + dt]);
        } else if (i < 71040) {               // uvec[j]
            int j = i - 70976; float s = 0.f;
            for (int c = 0; c < 64; ++c) s += ln_g[c] * wq[c * 64 + j];
            uvec[j] = s;
        } else if (i < 71104) {               // w0vec[j]
            int j = i - 71040; float s = 0.f;
            for (int c = 0; c < 64; ++c) s += ln_b[c] * wq[c * 64 + j];
            w0vec[j] = s;
        } else if (i < 71168) {               // bn1 s/b
            int c = i - 71104;
            float s1 = bn1_g[c] * rsqrtf(bn1_v[c] + BN_EPS);
            bnc[c]      = s1;
            bnc[64 + c] = bn1_b[c] - bn1_m[c] * s1;
        } else if (i < 71232) {               // bn2 s/b
            int c = i - 71168;
            float s2 = bn2_g[c] * rsqrtf(bn2_v[c] + BN_EPS);
            bnc[128 + c] = s2;
            bnc[192 + c] = bn2_b[c] - bn2_m[c] * s2;
        } else {                              // bn3 s / pre (incl tconv bias)
            int c = i - 71232;
            float s3 = bn3_g[c] * rsqrtf(bn3_v[c] + BN_EPS);
            bnc[256 + c] = s3;
            bnc[320 + c] = tconv_b[c] * s3 + (bn3_b[c] - bn3_m[c] * s3);
        }
    }
}

// ---------------------------------------------------------------------------
// scn R27 = R26-validated phases + T-PAIRING (T14 async-STAGE, validated
// pattern): each block processes t0=2*tp and t0+1. ALL x-loads for both t
// issued up front (14 regs) -> t1's ~900cy HBM latency fully hidden under
// t0's A..F compute; launch overhead halved (grid 16384->8192); zero-fills
// (INPV v-pads, VVT span) hoisted out of the loop (never overwritten).
// LDS buffers reused across iterations; loop-top barrier fences the
// XHT/INPT write-after-read. #pragma unroll keeps reg indices static.
// ---------------------------------------------------------------------------
#define OFF_INPV  0        // bf16 [64][40] (P0->A) / XHT [25][72] (E->F)
#define OFF_XHT   0
#define OFF_INPT  5120     // bf16 [25][72] (P0->F)
#define OFF_VVT   8720     // bf16 [64][40] (zeroed once; A->E)
#define OFF_Q2    13840    // bf16 [25][72] (A->D1)
#define OFF_ATT   13840    // bf16 [4][25][40] (D2->E), overlays Q2+K2+LNS
#define OFF_K2    17440    // bf16 [25][72] (A->D1)
#define OFF_LNS   21040    // f32 [25][4][2] (A->B0)
#define OFF_MU    21840    // f32 [25] (B0->B1C)
#define OFF_RSTD  21940    // f32 [25]
#define OFF_YT    22040    // bf16 [25][200] (A->B1C) / S f32 [4][25][25]
#define OFF_S     22040
#define LDS_BYTES 32040

#define LDSF(off) ((float*)(s_raw + (off)))
#define LDSH(off) ((u16*)(s_raw + (off)))
#define LDSV8(b)  (*(const bf16x8*)(s_raw + (b)))

__global__ __launch_bounds__(256) void scn_kernel(
    const float* __restrict__ x,
    const u16* __restrict__ akt, const u16* __restrict__ wp2,
    const u16* __restrict__ wqt, const u16* __restrict__ wkt,
    const u16* __restrict__ wvt, const u16* __restrict__ fct,
    const float* __restrict__ bagg,
    const float* __restrict__ uvec, const float* __restrict__ w0vec,
    const float* __restrict__ gate_w, const float* __restrict__ bnc,
    u16* __restrict__ f_out)
{
    const int bid  = blockIdx.x;
    const int n    = bid >> 8;          // 256 t-pairs per n
    const int t0   = (bid & 255) * 2;
    const int tid  = threadIdx.x;
    const int lane = tid & 63;
    const int wid  = tid >> 6;
    const int r0   = lane & 15;
    const int g    = lane >> 4;
    const int l31  = lane & 31;
    const int kh   = lane >> 5;

    __shared__ __align__(16) unsigned char s_raw[LDS_BYTES];

    const float gate = gate_w[0];

    // ---- Prefetch BOTH t-slices' x into registers (T14: issue-early) ----
    float xr[14];
    int ci7[7], vi7[7];
    #pragma unroll
    for (int it = 0; it < 7; ++it) {
        int i = tid + it * 256;
        int c = (i < 1600) ? (i / 25) : 0;
        int v = (i < 1600) ? (i - c * 25) : 0;
        ci7[it] = c; vi7[it] = v;
        const float* p = &x[((n * 64 + c) * 512 + t0) * 25 + v];
        xr[it]     = (i < 1600) ? p[0]  : 0.f;   // t0
        xr[7 + it] = (i < 1600) ? p[25] : 0.f;   // t0+1
    }

    // ---- one-time zero-fills (pads never overwritten by either iter) ----
    for (int i = tid; i < 960; i += 256) {
        int c = i / 15, vz = 25 + (i - c * 15);
        LDSH(OFF_INPV)[c * 40 + vz] = 0;
    }
    {
        bf16x8 z = {0,0,0,0,0,0,0,0};
        for (int i = tid; i < 320; i += 256)
            *(bf16x8*)(s_raw + OFF_VVT + i * 16) = z;
    }

    #pragma unroll
    for (int tt = 0; tt < 2; ++tt) {
        const int t = t0 + tt;
        __syncthreads();   // zero-fill visible (tt=0) / XHT,INPT reads done (tt=1)

        // ---- P0: bn1(x) from prefetched regs -> INPV, INPT ----
        #pragma unroll
        for (int it = 0; it < 7; ++it) {
            int i = tid + it * 256;
            if (i < 1600) {
                int c = ci7[it], v = vi7[it];
                float f = xr[tt * 7 + it] * bnc[c] + bnc[64 + c];
                u16 hb = f2bf1(f);
                LDSH(OFF_INPV)[c * 40 + v] = hb;
                LDSH(OFF_INPT)[v * 72 + c] = hb;
            }
        }
        __syncthreads();

        // ---- Phase A: y-GEMM, k/v/q projections (MFMA), LN partials ----
        #pragma unroll
        for (int ii = 0; ii < 6; ++ii) {
            int idx = wid * 6 + ii;
            int k = idx >> 3, rem = idx & 7, mt = rem >> 1, ntt = rem & 1;
            bf16x8 a = LDSV8(OFF_INPV + ((mt * 16 + r0) * 40 + g * 8) * 2);
            bf16x8 b = *(const bf16x8*)(&akt[(k * 32 + ntt * 16 + r0) * 40 + g * 8]);
            f32x4 acc = {0.f, 0.f, 0.f, 0.f};
            acc = MFMA(a, b, acc);
            int w = ntt * 16 + r0, cb = mt * 16 + g * 4;
            if (w < 25)
                *(u32x2*)&LDSH(OFF_YT)[w * 200 + k * 64 + cb] = pack4(acc);
        }
        // k-proj (swapped)
        #pragma unroll
        for (int ii = 0; ii < 2; ++ii) {
            int idx = wid * 2 + ii, mtj = idx >> 1, ntv = idx & 1;
            f32x4 acc = {0.f, 0.f, 0.f, 0.f};
            #pragma unroll
            for (int ks = 0; ks < 2; ++ks) {
                bf16x8 a = *(const bf16x8*)(&wkt[(mtj * 16 + r0) * 64 + ks * 32 + g * 8]);
                bf16x8 b = LDSV8(OFF_INPT + ((ntv * 16 + r0) * 72 + ks * 32 + g * 8) * 2);
                acc = MFMA(a, b, acc);
            }
            int v = ntv * 16 + r0;
            if (v < 25)
                *(u32x2*)&LDSH(OFF_K2)[v * 72 + mtj * 16 + g * 4] = pack4(acc);
        }
        // v-proj
        #pragma unroll
        for (int ii = 0; ii < 2; ++ii) {
            int idx = wid * 2 + ii, mt = idx >> 2, ntt = idx & 3;
            f32x4 acc = {0.f, 0.f, 0.f, 0.f};
            #pragma unroll
            for (int ks = 0; ks < 2; ++ks) {
                bf16x8 a = LDSV8(OFF_INPT + ((mt * 16 + r0) * 72 + ks * 32 + g * 8) * 2);
                bf16x8 b = *(const bf16x8*)(&wvt[(ntt * 16 + r0) * 64 + ks * 32 + g * 8]);
                acc = MFMA(a, b, acc);
            }
            int j = ntt * 16 + r0;
            #pragma unroll
            for (int r = 0; r < 4; ++r) {
                int v = mt * 16 + g * 4 + r;
                if (v < 25) LDSH(OFF_VVT)[j * 40 + v] = f2bf1(acc[r]);
            }
        }
        // q-proj (swapped, g-scaled)
        #pragma unroll
        for (int ii = 0; ii < 2; ++ii) {
            int idx = wid * 2 + ii, mtj = idx >> 1, ntv = idx & 1;
            f32x4 acc = {0.f, 0.f, 0.f, 0.f};
            #pragma unroll
            for (int ks = 0; ks < 2; ++ks) {
                bf16x8 a = *(const bf16x8*)(&wqt[(mtj * 16 + r0) * 64 + ks * 32 + g * 8]);
                bf16x8 b = LDSV8(OFF_INPT + ((ntv * 16 + r0) * 72 + ks * 32 + g * 8) * 2);
                acc = MFMA(a, b, acc);
            }
            int v = ntv * 16 + r0;
            if (v < 25)
                *(u32x2*)&LDSH(OFF_Q2)[v * 72 + mtj * 16 + g * 4] = pack4(acc);
        }
        // LN partials
        if (tid < 100) {
            int v = tid >> 2, p = tid & 3;
            const u16* row = LDSH(OFF_INPT) + v * 72 + p * 16;
            float s1 = 0.f, s2 = 0.f;
            #pragma unroll
            for (int cc = 0; cc < 16; ++cc) {
                float xv = bf2f(row[cc]);
                s1 += xv; s2 += xv * xv;
            }
            LDSF(OFF_LNS)[(v * 4 + p) * 2]     = s1;
            LDSF(OFF_LNS)[(v * 4 + p) * 2 + 1] = s2;
        }
        __syncthreads();

        // ---- B0: LN reduce ----
        if (tid < 25) {
            float s1 = 0.f, s2 = 0.f;
            #pragma unroll
            for (int p = 0; p < 4; ++p) {
                s1 += LDSF(OFF_LNS)[(tid * 4 + p) * 2];
                s2 += LDSF(OFF_LNS)[(tid * 4 + p) * 2 + 1];
            }
            float mu = s1 * (1.f / 64.f);
            float var = s2 * (1.f / 64.f) - mu * mu;
            LDSF(OFF_MU)[tid]   = mu;
            LDSF(OFF_RSTD)[tid] = rsqrtf(var + LN_EPS);
        }
        __syncthreads();

        // ---- B1C: Q2 fixup (0.25 folded) + agg-GEMM (regs) ----
        #pragma unroll
        for (int it = 0; it < 7; ++it) {
            int i = tid + it * 256;
            if (i < 1600) {
                int v = i >> 6, j = i & 63;
                float raw = bf2f(LDSH(OFF_Q2)[v * 72 + j]);
                float rs = LDSF(OFF_RSTD)[v], m = LDSF(OFF_MU)[v];
                LDSH(OFF_Q2)[v * 72 + j] =
                    f2bf1(0.25f * (rs * raw - rs * m * uvec[j] + w0vec[j]));
            }
        }
        f32x4 agg_reg[2];
        #pragma unroll
        for (int ii = 0; ii < 2; ++ii) {
            int idx = wid * 2 + ii, mt = idx >> 1, ntt = idx & 1;
            f32x4 acc = {0.f, 0.f, 0.f, 0.f};
            #pragma unroll
            for (int ks = 0; ks < 6; ++ks) {
                bf16x8 a = *(const bf16x8*)(&wp2[(mt * 16 + r0) * 192 + ks * 32 + g * 8]);
                int brow = ntt * 16 + r0; if (brow > 24) brow = 24;
                bf16x8 b = LDSV8(OFF_YT + (brow * 200 + ks * 32 + g * 8) * 2);
                acc = MFMA(a, b, acc);
            }
            int w = ntt * 16 + r0, cb = mt * 16 + g * 4;
            if (w < 25) {
                #pragma unroll
                for (int r = 0; r < 4; ++r) acc[r] += bagg[(cb + r) * 25 + w];
            }
            agg_reg[ii] = acc;
        }
        __syncthreads();

        // ---- D1 (32x32x16, K=16=DK; head h == wid) -> S f32 [4][25][25] ----
        {
            const int h = wid;
            bf16x8 a = LDSV8(OFF_Q2 + (l31 * 72 + h * 16 + kh * 8) * 2);
            bf16x8 b = LDSV8(OFF_K2 + (l31 * 72 + h * 16 + kh * 8) * 2);
            f32x16 acc = {};
            acc = MFMA32(a, b, acc);
            int kv = l31;
            if (kv < 25) {
                #pragma unroll
                for (int reg = 0; reg < 16; ++reg) {
                    int qv = (reg & 3) + 8 * (reg >> 2) + 4 * kh;
                    if (qv < 25)
                        LDSF(OFF_S)[(h * 25 + qv) * 25 + kv] = acc[reg];
                }
            }
        }
        __syncthreads();

        // ---- D2: softmax -> ATT (packed u32 stores via cvt_pk) ----
        if (tid < 100) {
            int h = tid / 25, qv = tid - h * 25;
            const float* srow = LDSF(OFF_S) + (h * 25 + qv) * 25;
            float row[25]; float mx = -1e30f;
            #pragma unroll
            for (int kv = 0; kv < 25; ++kv) {
                float s = srow[kv];
                row[kv] = s; mx = fmaxf(mx, s);
            }
            float sum = 0.f;
            #pragma unroll
            for (int kv = 0; kv < 25; ++kv) { float e = __expf(row[kv] - mx); row[kv] = e; sum += e; }
            float inv = 1.f / sum;
            u32* arow32 = (u32*)(LDSH(OFF_ATT) + (h * 25 + qv) * 40);
            #pragma unroll
            for (int p = 0; p < 12; ++p)
                arow32[p] = cvtpk(row[2 * p] * inv, row[2 * p + 1] * inv);
            arow32[12] = cvtpk(row[24] * inv, 0.f);
            arow32[13] = 0; arow32[14] = 0; arow32[15] = 0;
        }
        __syncthreads();

        // ---- E (32x32x16, 2 K-steps; head h == wid): xh = P@V -> XHT ----
        {
            const int h = wid;
            f32x16 acc = {};
            #pragma unroll
            for (int step = 0; step < 2; ++step) {
                bf16x8 a = LDSV8(OFF_ATT + ((h * 25 + l31) * 40 + step * 16 + kh * 8) * 2);
                bf16x8 b = LDSV8(OFF_VVT + ((h * 16 + l31) * 40 + step * 16 + kh * 8) * 2);
                acc = MFMA32(a, b, acc);
            }
            int d = l31;
            if (d < 16) {
                #pragma unroll
                for (int reg = 0; reg < 16; ++reg) {
                    int qv = (reg & 3) + 8 * (reg >> 2) + 4 * kh;
                    if (qv < 25)
                        LDSH(OFF_XHT)[qv * 72 + h * 16 + d] = f2bf1(acc[reg]);
                }
            }
        }
        __syncthreads();

        // ---- F: fc-GEMM + fused epilogue -> f bf16 ----
        #pragma unroll
        for (int ii = 0; ii < 2; ++ii) {
            int idx = wid * 2 + ii, mt = idx >> 1, ntt = idx & 1;
            f32x4 acc = {0.f, 0.f, 0.f, 0.f};
            #pragma unroll
            for (int ks = 0; ks < 2; ++ks) {
                bf16x8 a = *(const bf16x8*)(&fct[(mt * 16 + r0) * 64 + ks * 32 + g * 8]);
                bf16x8 b = LDSV8(OFF_XHT + ((ntt * 16 + r0) * 72 + ks * 32 + g * 8) * 2);
                acc = MFMA(a, b, acc);
            }
            int v = ntt * 16 + r0;
            if (v < 25) {
                int cb = mt * 16 + g * 4;
                float fv[4];
                #pragma unroll
                for (int r = 0; r < 4; ++r) {
                    int c = cb + r;
                    float fa_out = acc[r] + bf2f(LDSH(OFF_INPT)[v * 72 + c]);
                    float t1 = (fa_out * gate + agg_reg[ii][r]) * 0.5f;
                    fv[r] = fmaxf(t1 * bnc[128 + c] + bnc[192 + c], 0.f);
                }
                u32x2 pk;
                pk[0] = cvtpk(fv[0], fv[1]);
                pk[1] = cvtpk(fv[2], fv[3]);
                *(u32x2*)&f_out[((n * 512 + t) * 25 + v) * 64 + cb] = pk;
            }
        }
    }
}

// ---------------------------------------------------------------------------
// tcn_mfma: implicit-GEMM temporal conv (R13/R20-validated, ~40us floor).
// ---------------------------------------------------------------------------
#define FB_STRIDE 40

__global__ __launch_bounds__(256) void tcn_mfma(
    const u16* __restrict__ f, const float* __restrict__ x,
    const u16* __restrict__ wtc, const float* __restrict__ bnc,
    float* __restrict__ out)
{
    const int bid  = blockIdx.x;
    const int n    = bid >> 5;
    const int t0   = (bid & 31) * 16;
    const int tid  = threadIdx.x;
    const int lane = tid & 63;
    const int wid  = tid >> 6;
    const int r0   = lane & 15;
    const int g    = lane >> 4;
    const int co_base = wid * 16;

    __shared__ __align__(16) u16 s_fB[24 * 25 * FB_STRIDE];

    f32x4 acc[25];
    #pragma unroll
    for (int i = 0; i < 25; ++i) acc[i] = (f32x4){0.f, 0.f, 0.f, 0.f};

    for (int ph = 0; ph < 2; ++ph) {
        const int ci0 = ph * 32;
        __syncthreads();
        for (int u = tid; u < 2400; u += 256) {
            int q = u & 3, rv = u >> 2;
            int tp = rv / 25, v = rv - tp * 25;
            int tg = t0 + tp - 4;
            bf16x8 val = {0,0,0,0,0,0,0,0};
            if (tg >= 0 && tg < 512)
                val = *(const bf16x8*)&f[((n * 512 + tg) * 25 + v) * 64 + ci0 + q * 8];
            *(bf16x8*)&s_fB[rv * FB_STRIDE + q * 8] = val;
        }
        __syncthreads();

        bf16x8 aF[9];
        #pragma unroll
        for (int dt = 0; dt < 9; ++dt)
            aF[dt] = *(const bf16x8*)(&wtc[((co_base + r0) * 9 + dt) * 64 + ci0 + g * 8]);

        #pragma unroll
        for (int nt2 = 0; nt2 < 25; ++nt2) {
            int c0 = nt2 * 16 + r0;
            int tb = c0 / 25, v = c0 - tb * 25;
            #pragma unroll
            for (int dt = 0; dt < 9; ++dt) {
                bf16x8 bF = *(const bf16x8*)(&s_fB[((tb + dt) * 25 + v) * FB_STRIDE + g * 8]);
                acc[nt2] = MFMA(aF[dt], bF, acc[nt2]);
            }
        }
    }

    float s3v[4], pre[4];
    #pragma unroll
    for (int r = 0; r < 4; ++r) {
        int co = co_base + g * 4 + r;
        s3v[r] = bnc[256 + co];
        pre[r] = bnc[320 + co];
    }
    #pragma unroll
    for (int nt2 = 0; nt2 < 25; ++nt2) {
        int c0 = nt2 * 16 + r0;
        int tb = c0 / 25, v = c0 - tb * 25;
        #pragma unroll
        for (int r = 0; r < 4; ++r) {
            int co = co_base + g * 4 + r;
            int idx = ((n * 64 + co) * 512 + t0 + tb) * 25 + v;
            float y = acc[nt2][r] * s3v[r] + pre[r] + x[idx];
            out[idx] = fmaxf(y, 0.f);
        }
    }
}

extern "C" void kernel_launch(void* const* d_in, const int* in_sizes, int n_in,
                              void* d_out, int out_size, void* d_ws, size_t ws_size,
                              hipStream_t stream) {
    const float* x       = (const float*)d_in[0];
    const float* A       = (const float*)d_in[1];
    const float* bn1_g   = (const float*)d_in[2];
    const float* bn1_b   = (const float*)d_in[3];
    const float* bn1_m   = (const float*)d_in[4];
    const float* bn1_v   = (const float*)d_in[5];
    const float* pconv_w = (const float*)d_in[6];
    const float* pconv_b = (const float*)d_in[7];
    const float* wq      = (const float*)d_in[8];
    const float* wk      = (const float*)d_in[9];
    const float* wv      = (const float*)d_in[10];
    const float* fc_w    = (const float*)d_in[11];
    const float* ln_g    = (const float*)d_in[12];
    const float* ln_b    = (const float*)d_in[13];
    const float* gate_w  = (const float*)d_in[14];
    const float* bn2_g   = (const float*)d_in[15];
    const float* bn2_b   = (const float*)d_in[16];
    const float* bn2_m   = (const float*)d_in[17];
    const float* bn2_v   = (const float*)d_in[18];
    const float* tconv_w = (const float*)d_in[19];
    const float* tconv_b = (const float*)d_in[20];
    const float* bn3_g   = (const float*)d_in[21];
    const float* bn3_b   = (const float*)d_in[22];
    const float* bn3_m   = (const float*)d_in[23];
    const float* bn3_v   = (const float*)d_in[24];

    char* ws = (char*)d_ws;
    u16*   f_bf  = (u16*)ws;
    u16*   akt   = (u16*)(ws + WOFF);
    u16*   wp2   = (u16*)(ws + WOFF + 7680);
    u16*   wqt   = (u16*)(ws + WOFF + 32256);
    u16*   wkt   = (u16*)(ws + WOFF + 40448);
    u16*   wvt   = (u16*)(ws + WOFF + 48640);
    u16*   fct   = (u16*)(ws + WOFF + 56832);
    float* bagg  = (float*)(ws + WOFF + 65024);
    u16*   wtc   = (u16*)(ws + WOFF + 71424);
    float* uvec  = (float*)(ws + WOFF + 145152);
    float* w0vec = (float*)(ws + WOFF + 145408);
    float* bnc   = (float*)(ws + WOFF + 145664);
    float* outp  = (float*)d_out;

    prep_kernel<<<dim3(64), dim3(256), 0, stream>>>(
        A, pconv_w, pconv_b, wq, wk, wv, fc_w, tconv_w, tconv_b, ln_g, ln_b,
        bn1_g, bn1_b, bn1_m, bn1_v, bn2_g, bn2_b, bn2_m, bn2_v,
        bn3_g, bn3_b, bn3_m, bn3_v,
        akt, wp2, wqt, wkt, wvt, fct, bagg, wtc, uvec, w0vec, bnc);
    scn_kernel<<<dim3(NB * 256), dim3(256), 0, stream>>>(
        x, akt, wp2, wqt, wkt, wvt, fct, bagg, uvec, w0vec, gate_w, bnc, f_bf);
    tcn_mfma<<<dim3(NB * 32), dim3(256), 0, stream>>>(
        f_bf, x, wtc, bnc, outp);
}

// Round 28
// 314.485 us; speedup vs baseline: 1.1819x; 1.1819x over previous
//
#include <hip/hip_runtime.h>

#define NB   32
#define C    64
#define T    512
#define V    25
#define KP   3
#define CO   64
#define H    4
#define BN_EPS 1e-5f
#define LN_EPS 1e-6f

typedef float f32x4 __attribute__((ext_vector_type(4)));
typedef float f32x16 __attribute__((ext_vector_type(16)));
typedef short bf16x8 __attribute__((ext_vector_type(8)));
typedef unsigned short u16;
typedef unsigned int u32;
typedef u32 u32x2 __attribute__((ext_vector_type(2)));
#define MFMA(a,b,c)   __builtin_amdgcn_mfma_f32_16x16x32_bf16((a),(b),(c),0,0,0)
#define MFMA32(a,b,c) __builtin_amdgcn_mfma_f32_32x32x16_bf16((a),(b),(c),0,0,0)

__device__ __forceinline__ u16 f2bf(float x) {          // prep-side (cold)
    union { float f; unsigned u; } v; v.f = x;
    unsigned r = (v.u + 0x7FFFu + ((v.u >> 16) & 1u)) >> 16;
    return (u16)r;
}
__device__ __forceinline__ float bf2f(u16 h) {
    union { unsigned u; float f; } v; v.u = ((unsigned)h) << 16;
    return v.f;
}
// HW packed convert (gfx950, RNE; guide T12 recipe, HW-verified m214v22)
__device__ __forceinline__ u32 cvtpk(float lo, float hi) {
    u32 r;
    asm("v_cvt_pk_bf16_f32 %0, %1, %2" : "=v"(r) : "v"(lo), "v"(hi));
    return r;
}
__device__ __forceinline__ u16 f2bf1(float x) { return (u16)cvtpk(x, x); }
__device__ __forceinline__ u32x2 pack4(const f32x4& a) {
    u32x2 p;
    p[0] = cvtpk(a[0], a[1]);
    p[1] = cvtpk(a[2], a[3]);
    return p;
}

#define WOFF 52428800ull

// prep R20-validated: weights + BN affine constants
__global__ __launch_bounds__(256) void prep_kernel(
    const float* __restrict__ A, const float* __restrict__ pconv_w,
    const float* __restrict__ pconv_b,
    const float* __restrict__ wq, const float* __restrict__ wk,
    const float* __restrict__ wv, const float* __restrict__ fc_w,
    const float* __restrict__ tconv_w, const float* __restrict__ tconv_b,
    const float* __restrict__ ln_g, const float* __restrict__ ln_b,
    const float* __restrict__ bn1_g, const float* __restrict__ bn1_b,
    const float* __restrict__ bn1_m, const float* __restrict__ bn1_v,
    const float* __restrict__ bn2_g, const float* __restrict__ bn2_b,
    const float* __restrict__ bn2_m, const float* __restrict__ bn2_v,
    const float* __restrict__ bn3_g, const float* __restrict__ bn3_b,
    const float* __restrict__ bn3_m, const float* __restrict__ bn3_v,
    u16* __restrict__ akt, u16* __restrict__ wp2,
    u16* __restrict__ wqt, u16* __restrict__ wkt, u16* __restrict__ wvt,
    u16* __restrict__ fct, float* __restrict__ bagg, u16* __restrict__ wtc,
    float* __restrict__ uvec, float* __restrict__ w0vec,
    float* __restrict__ bnc)
{
    const int stride = gridDim.x * 256;
    for (int i = blockIdx.x * 256 + threadIdx.x; i < 71296; i += stride) {
        if (i < 3840) {                       // AkT
            int k = i / 1280, r = i - k * 1280, w = r / 40, v = r - w * 40;
            float val = (w < V && v < V) ? A[k * V * V + v * V + w] : 0.f;
            akt[i] = f2bf(val);
        } else if (i < 16128) {               // Wp2
            int i2 = i - 3840;
            int c = i2 / 192, kk = i2 - c * 192, k = kk / 64, ci = kk - k * 64;
            wp2[i2] = f2bf(pconv_w[(k * 64 + c) * 64 + ci]);
        } else if (i < 20224) {               // WqT (ln_g-scaled)
            int i2 = i - 16128; int j = i2 / 64, c = i2 - j * 64;
            wqt[i2] = f2bf(wq[c * 64 + j] * ln_g[c]);
        } else if (i < 24320) {               // WkT
            int i2 = i - 20224; int j = i2 / 64, c = i2 - j * 64;
            wkt[i2] = f2bf(wk[c * 64 + j]);
        } else if (i < 28416) {               // WvT
            int i2 = i - 24320; int j = i2 / 64, c = i2 - j * 64;
            wvt[i2] = f2bf(wv[c * 64 + j]);
        } else if (i < 32512) {               // FcT
            int i2 = i - 28416; int c = i2 / 64, d = i2 - c * 64;
            fct[i2] = f2bf(fc_w[d * 64 + c]);
        } else if (i < 34112) {               // bias_agg
            int i2 = i - 32512; int c = i2 / 25, w = i2 - c * 25;
            float s = 0.f;
            for (int k = 0; k < KP; ++k) {
                float cs = 0.f;
                for (int v = 0; v < V; ++v) cs += A[k * V * V + v * V + w];
                s += pconv_b[k * 64 + c] * cs;
            }
            bagg[i2] = s;
        } else if (i < 70976) {               // Wtc
            int i2 = i - 34112;
            int co = i2 / 576, rem = i2 - co * 576, dt = rem / 64, ci = rem - dt * 64;
            wtc[i2] = f2bf(tconv_w[(co * 64 + ci) * 9 + dt]);
        } else if (i < 71040) {               // uvec[j]
            int j = i - 70976; float s = 0.f;
            for (int c = 0; c < 64; ++c) s += ln_g[c] * wq[c * 64 + j];
            uvec[j] = s;
        } else if (i < 71104) {               // w0vec[j]
            int j = i - 71040; float s = 0.f;
            for (int c = 0; c < 64; ++c) s += ln_b[c] * wq[c * 64 + j];
            w0vec[j] = s;
        } else if (i < 71168) {               // bn1 s/b
            int c = i - 71104;
            float s1 = bn1_g[c] * rsqrtf(bn1_v[c] + BN_EPS);
            bnc[c]      = s1;
            bnc[64 + c] = bn1_b[c] - bn1_m[c] * s1;
        } else if (i < 71232) {               // bn2 s/b
            int c = i - 71168;
            float s2 = bn2_g[c] * rsqrtf(bn2_v[c] + BN_EPS);
            bnc[128 + c] = s2;
            bnc[192 + c] = bn2_b[c] - bn2_m[c] * s2;
        } else {                              // bn3 s / pre (incl tconv bias)
            int c = i - 71232;
            float s3 = bn3_g[c] * rsqrtf(bn3_v[c] + BN_EPS);
            bnc[256 + c] = s3;
            bnc[320 + c] = tconv_b[c] * s3 + (bn3_b[c] - bn3_m[c] * s3);
        }
    }
}

// ---------------------------------------------------------------------------
// scn R28 = exact revert to R26-validated (234us scn, 314.7us total, absmax
// 0.03125; 20.9x over baseline). R27's t-pairing REGRESSED (234->282us):
// 14 prefetch regs + duplicated loop state pushed VGPR 44->88, occupancy
// 44->22% -- same occupancy-loss failure family as R4/R13. This kernel's
// latency hiding is cross-block TLP; protect 4 blocks/CU above all.
// Plateau: last five structural attempts (R21 butterfly-SM, R23 barrier-drop,
// R24 5-block, R26 LDS-shave, R27 t-pair) measured 0/-13/-4(partial)/0/-17%.
// Remaining path would be HK-style wave-specialization (multi-round, 3
// attempts in that family failed A/B). Locking in validated state.
// ---------------------------------------------------------------------------
#define OFF_INPV  0        // bf16 [64][40] (P0->A) / XHT [25][72] (E->F)
#define OFF_XHT   0
#define OFF_INPT  5120     // bf16 [25][72] (P0->F)
#define OFF_VVT   8720     // bf16 [64][40] (zeroed P0; A->E)
#define OFF_Q2    13840    // bf16 [25][72] (A->D1)
#define OFF_ATT   13840    // bf16 [4][25][40] (D2->E), overlays Q2+K2+LNS
#define OFF_K2    17440    // bf16 [25][72] (A->D1)
#define OFF_LNS   21040    // f32 [25][4][2] (A->B0)
#define OFF_MU    21840    // f32 [25] (B0->B1C)
#define OFF_RSTD  21940    // f32 [25]
#define OFF_YT    22040    // bf16 [25][200] (A->B1C) / S f32 [4][25][25]
#define OFF_S     22040
#define LDS_BYTES 32040

#define LDSF(off) ((float*)(s_raw + (off)))
#define LDSH(off) ((u16*)(s_raw + (off)))
#define LDSV8(b)  (*(const bf16x8*)(s_raw + (b)))

__global__ __launch_bounds__(256) void scn_kernel(
    const float* __restrict__ x,
    const u16* __restrict__ akt, const u16* __restrict__ wp2,
    const u16* __restrict__ wqt, const u16* __restrict__ wkt,
    const u16* __restrict__ wvt, const u16* __restrict__ fct,
    const float* __restrict__ bagg,
    const float* __restrict__ uvec, const float* __restrict__ w0vec,
    const float* __restrict__ gate_w, const float* __restrict__ bnc,
    u16* __restrict__ f_out)
{
    const int nt   = blockIdx.x;
    const int n    = nt >> 9;
    const int t    = nt & 511;
    const int tid  = threadIdx.x;
    const int lane = tid & 63;
    const int wid  = tid >> 6;
    const int r0   = lane & 15;
    const int g    = lane >> 4;
    const int l31  = lane & 31;
    const int kh   = lane >> 5;

    __shared__ __align__(16) unsigned char s_raw[LDS_BYTES];

    const float gate = gate_w[0];

    // ---- P0 ----
    #pragma unroll
    for (int it = 0; it < 7; ++it) {
        int i = tid + it * 256;
        if (i < 1600) {
            int c = i / 25, v = i - c * 25;
            float f = x[((n * 64 + c) * 512 + t) * 25 + v] * bnc[c] + bnc[64 + c];
            u16 hb = f2bf1(f);
            LDSH(OFF_INPV)[c * 40 + v] = hb;
            LDSH(OFF_INPT)[v * 72 + c] = hb;
        }
    }
    for (int i = tid; i < 960; i += 256) {
        int c = i / 15, vz = 25 + (i - c * 15);
        LDSH(OFF_INPV)[c * 40 + vz] = 0;
    }
    {
        bf16x8 z = {0,0,0,0,0,0,0,0};
        for (int i = tid; i < 320; i += 256)
            *(bf16x8*)(s_raw + OFF_VVT + i * 16) = z;
    }
    __syncthreads();

    // ---- Phase A ----
    #pragma unroll
    for (int ii = 0; ii < 6; ++ii) {
        int idx = wid * 6 + ii;
        int k = idx >> 3, rem = idx & 7, mt = rem >> 1, ntt = rem & 1;
        bf16x8 a = LDSV8(OFF_INPV + ((mt * 16 + r0) * 40 + g * 8) * 2);
        bf16x8 b = *(const bf16x8*)(&akt[(k * 32 + ntt * 16 + r0) * 40 + g * 8]);
        f32x4 acc = {0.f, 0.f, 0.f, 0.f};
        acc = MFMA(a, b, acc);
        int w = ntt * 16 + r0, cb = mt * 16 + g * 4;
        if (w < 25)
            *(u32x2*)&LDSH(OFF_YT)[w * 200 + k * 64 + cb] = pack4(acc);
    }
    // k-proj (swapped)
    #pragma unroll
    for (int ii = 0; ii < 2; ++ii) {
        int idx = wid * 2 + ii, mtj = idx >> 1, ntv = idx & 1;
        f32x4 acc = {0.f, 0.f, 0.f, 0.f};
        #pragma unroll
        for (int ks = 0; ks < 2; ++ks) {
            bf16x8 a = *(const bf16x8*)(&wkt[(mtj * 16 + r0) * 64 + ks * 32 + g * 8]);
            bf16x8 b = LDSV8(OFF_INPT + ((ntv * 16 + r0) * 72 + ks * 32 + g * 8) * 2);
            acc = MFMA(a, b, acc);
        }
        int v = ntv * 16 + r0;
        if (v < 25)
            *(u32x2*)&LDSH(OFF_K2)[v * 72 + mtj * 16 + g * 4] = pack4(acc);
    }
    // v-proj
    #pragma unroll
    for (int ii = 0; ii < 2; ++ii) {
        int idx = wid * 2 + ii, mt = idx >> 2, ntt = idx & 3;
        f32x4 acc = {0.f, 0.f, 0.f, 0.f};
        #pragma unroll
        for (int ks = 0; ks < 2; ++ks) {
            bf16x8 a = LDSV8(OFF_INPT + ((mt * 16 + r0) * 72 + ks * 32 + g * 8) * 2);
            bf16x8 b = *(const bf16x8*)(&wvt[(ntt * 16 + r0) * 64 + ks * 32 + g * 8]);
            acc = MFMA(a, b, acc);
        }
        int j = ntt * 16 + r0;
        #pragma unroll
        for (int r = 0; r < 4; ++r) {
            int v = mt * 16 + g * 4 + r;
            if (v < 25) LDSH(OFF_VVT)[j * 40 + v] = f2bf1(acc[r]);
        }
    }
    // q-proj (swapped, g-scaled)
    #pragma unroll
    for (int ii = 0; ii < 2; ++ii) {
        int idx = wid * 2 + ii, mtj = idx >> 1, ntv = idx & 1;
        f32x4 acc = {0.f, 0.f, 0.f, 0.f};
        #pragma unroll
        for (int ks = 0; ks < 2; ++ks) {
            bf16x8 a = *(const bf16x8*)(&wqt[(mtj * 16 + r0) * 64 + ks * 32 + g * 8]);
            bf16x8 b = LDSV8(OFF_INPT + ((ntv * 16 + r0) * 72 + ks * 32 + g * 8) * 2);
            acc = MFMA(a, b, acc);
        }
        int v = ntv * 16 + r0;
        if (v < 25)
            *(u32x2*)&LDSH(OFF_Q2)[v * 72 + mtj * 16 + g * 4] = pack4(acc);
    }
    // LN partials
    if (tid < 100) {
        int v = tid >> 2, p = tid & 3;
        const u16* row = LDSH(OFF_INPT) + v * 72 + p * 16;
        float s1 = 0.f, s2 = 0.f;
        #pragma unroll
        for (int cc = 0; cc < 16; ++cc) {
            float xv = bf2f(row[cc]);
            s1 += xv; s2 += xv * xv;
        }
        LDSF(OFF_LNS)[(v * 4 + p) * 2]     = s1;
        LDSF(OFF_LNS)[(v * 4 + p) * 2 + 1] = s2;
    }
    __syncthreads();

    // ---- B0 ----
    if (tid < 25) {
        float s1 = 0.f, s2 = 0.f;
        #pragma unroll
        for (int p = 0; p < 4; ++p) {
            s1 += LDSF(OFF_LNS)[(tid * 4 + p) * 2];
            s2 += LDSF(OFF_LNS)[(tid * 4 + p) * 2 + 1];
        }
        float mu = s1 * (1.f / 64.f);
        float var = s2 * (1.f / 64.f) - mu * mu;
        LDSF(OFF_MU)[tid]   = mu;
        LDSF(OFF_RSTD)[tid] = rsqrtf(var + LN_EPS);
    }
    __syncthreads();

    // ---- B1C ----
    #pragma unroll
    for (int it = 0; it < 7; ++it) {
        int i = tid + it * 256;
        if (i < 1600) {
            int v = i >> 6, j = i & 63;
            float raw = bf2f(LDSH(OFF_Q2)[v * 72 + j]);
            float rs = LDSF(OFF_RSTD)[v], m = LDSF(OFF_MU)[v];
            LDSH(OFF_Q2)[v * 72 + j] =
                f2bf1(0.25f * (rs * raw - rs * m * uvec[j] + w0vec[j]));
        }
    }
    f32x4 agg_reg[2];
    #pragma unroll
    for (int ii = 0; ii < 2; ++ii) {
        int idx = wid * 2 + ii, mt = idx >> 1, ntt = idx & 1;
        f32x4 acc = {0.f, 0.f, 0.f, 0.f};
        #pragma unroll
        for (int ks = 0; ks < 6; ++ks) {
            bf16x8 a = *(const bf16x8*)(&wp2[(mt * 16 + r0) * 192 + ks * 32 + g * 8]);
            int brow = ntt * 16 + r0; if (brow > 24) brow = 24;
            bf16x8 b = LDSV8(OFF_YT + (brow * 200 + ks * 32 + g * 8) * 2);
            acc = MFMA(a, b, acc);
        }
        int w = ntt * 16 + r0, cb = mt * 16 + g * 4;
        if (w < 25) {
            #pragma unroll
            for (int r = 0; r < 4; ++r) acc[r] += bagg[(cb + r) * 25 + w];
        }
        agg_reg[ii] = acc;
    }
    __syncthreads();

    // ---- D1 (32x32x16, K=16=DK; head h == wid) -> S f32 [4][25][25] ----
    {
        const int h = wid;
        bf16x8 a = LDSV8(OFF_Q2 + (l31 * 72 + h * 16 + kh * 8) * 2);
        bf16x8 b = LDSV8(OFF_K2 + (l31 * 72 + h * 16 + kh * 8) * 2);
        f32x16 acc = {};
        acc = MFMA32(a, b, acc);
        int kv = l31;
        if (kv < 25) {
            #pragma unroll
            for (int reg = 0; reg < 16; ++reg) {
                int qv = (reg & 3) + 8 * (reg >> 2) + 4 * kh;
                if (qv < 25)
                    LDSF(OFF_S)[(h * 25 + qv) * 25 + kv] = acc[reg];
            }
        }
    }
    __syncthreads();

    // ---- D2: softmax -> ATT (packed u32 stores via cvt_pk) ----
    if (tid < 100) {
        int h = tid / 25, qv = tid - h * 25;
        const float* srow = LDSF(OFF_S) + (h * 25 + qv) * 25;
        float row[25]; float mx = -1e30f;
        #pragma unroll
        for (int kv = 0; kv < 25; ++kv) {
            float s = srow[kv];
            row[kv] = s; mx = fmaxf(mx, s);
        }
        float sum = 0.f;
        #pragma unroll
        for (int kv = 0; kv < 25; ++kv) { float e = __expf(row[kv] - mx); row[kv] = e; sum += e; }
        float inv = 1.f / sum;
        u32* arow32 = (u32*)(LDSH(OFF_ATT) + (h * 25 + qv) * 40);
        #pragma unroll
        for (int p = 0; p < 12; ++p)
            arow32[p] = cvtpk(row[2 * p] * inv, row[2 * p + 1] * inv);
        arow32[12] = cvtpk(row[24] * inv, 0.f);   // kv 24 + zero kv 25
        arow32[13] = 0; arow32[14] = 0; arow32[15] = 0;  // kv 26..31
    }
    __syncthreads();

    // ---- E (32x32x16, 2 K-steps; head h == wid): xh = P@V -> XHT ----
    {
        const int h = wid;
        f32x16 acc = {};
        #pragma unroll
        for (int step = 0; step < 2; ++step) {
            bf16x8 a = LDSV8(OFF_ATT + ((h * 25 + l31) * 40 + step * 16 + kh * 8) * 2);
            bf16x8 b = LDSV8(OFF_VVT + ((h * 16 + l31) * 40 + step * 16 + kh * 8) * 2);
            acc = MFMA32(a, b, acc);
        }
        int d = l31;
        if (d < 16) {
            #pragma unroll
            for (int reg = 0; reg < 16; ++reg) {
                int qv = (reg & 3) + 8 * (reg >> 2) + 4 * kh;
                if (qv < 25)
                    LDSH(OFF_XHT)[qv * 72 + h * 16 + d] = f2bf1(acc[reg]);
            }
        }
    }
    __syncthreads();

    // ---- F: fc-GEMM + fused epilogue -> f bf16 ----
    #pragma unroll
    for (int ii = 0; ii < 2; ++ii) {
        int idx = wid * 2 + ii, mt = idx >> 1, ntt = idx & 1;
        f32x4 acc = {0.f, 0.f, 0.f, 0.f};
        #pragma unroll
        for (int ks = 0; ks < 2; ++ks) {
            bf16x8 a = *(const bf16x8*)(&fct[(mt * 16 + r0) * 64 + ks * 32 + g * 8]);
            bf16x8 b = LDSV8(OFF_XHT + ((ntt * 16 + r0) * 72 + ks * 32 + g * 8) * 2);
            acc = MFMA(a, b, acc);
        }
        int v = ntt * 16 + r0;
        if (v < 25) {
            int cb = mt * 16 + g * 4;
            float fv[4];
            #pragma unroll
            for (int r = 0; r < 4; ++r) {
                int c = cb + r;
                float fa_out = acc[r] + bf2f(LDSH(OFF_INPT)[v * 72 + c]);
                float t1 = (fa_out * gate + agg_reg[ii][r]) * 0.5f;
                fv[r] = fmaxf(t1 * bnc[128 + c] + bnc[192 + c], 0.f);
            }
            u32x2 pk;
            pk[0] = cvtpk(fv[0], fv[1]);
            pk[1] = cvtpk(fv[2], fv[3]);
            *(u32x2*)&f_out[((n * 512 + t) * 25 + v) * 64 + cb] = pk;
        }
    }
}

// ---------------------------------------------------------------------------
// tcn_mfma: implicit-GEMM temporal conv (R13/R20-validated, ~40us floor).
// ---------------------------------------------------------------------------
#define FB_STRIDE 40

__global__ __launch_bounds__(256) void tcn_mfma(
    const u16* __restrict__ f, const float* __restrict__ x,
    const u16* __restrict__ wtc, const float* __restrict__ bnc,
    float* __restrict__ out)
{
    const int bid  = blockIdx.x;
    const int n    = bid >> 5;
    const int t0   = (bid & 31) * 16;
    const int tid  = threadIdx.x;
    const int lane = tid & 63;
    const int wid  = tid >> 6;
    const int r0   = lane & 15;
    const int g    = lane >> 4;
    const int co_base = wid * 16;

    __shared__ __align__(16) u16 s_fB[24 * 25 * FB_STRIDE];

    f32x4 acc[25];
    #pragma unroll
    for (int i = 0; i < 25; ++i) acc[i] = (f32x4){0.f, 0.f, 0.f, 0.f};

    for (int ph = 0; ph < 2; ++ph) {
        const int ci0 = ph * 32;
        __syncthreads();
        for (int u = tid; u < 2400; u += 256) {
            int q = u & 3, rv = u >> 2;
            int tp = rv / 25, v = rv - tp * 25;
            int tg = t0 + tp - 4;
            bf16x8 val = {0,0,0,0,0,0,0,0};
            if (tg >= 0 && tg < 512)
                val = *(const bf16x8*)&f[((n * 512 + tg) * 25 + v) * 64 + ci0 + q * 8];
            *(bf16x8*)&s_fB[rv * FB_STRIDE + q * 8] = val;
        }
        __syncthreads();

        bf16x8 aF[9];
        #pragma unroll
        for (int dt = 0; dt < 9; ++dt)
            aF[dt] = *(const bf16x8*)(&wtc[((co_base + r0) * 9 + dt) * 64 + ci0 + g * 8]);

        #pragma unroll
        for (int nt2 = 0; nt2 < 25; ++nt2) {
            int c0 = nt2 * 16 + r0;
            int tb = c0 / 25, v = c0 - tb * 25;
            #pragma unroll
            for (int dt = 0; dt < 9; ++dt) {
                bf16x8 bF = *(const bf16x8*)(&s_fB[((tb + dt) * 25 + v) * FB_STRIDE + g * 8]);
                acc[nt2] = MFMA(aF[dt], bF, acc[nt2]);
            }
        }
    }

    float s3v[4], pre[4];
    #pragma unroll
    for (int r = 0; r < 4; ++r) {
        int co = co_base + g * 4 + r;
        s3v[r] = bnc[256 + co];
        pre[r] = bnc[320 + co];
    }
    #pragma unroll
    for (int nt2 = 0; nt2 < 25; ++nt2) {
        int c0 = nt2 * 16 + r0;
        int tb = c0 / 25, v = c0 - tb * 25;
        #pragma unroll
        for (int r = 0; r < 4; ++r) {
            int co = co_base + g * 4 + r;
            int idx = ((n * 64 + co) * 512 + t0 + tb) * 25 + v;
            float y = acc[nt2][r] * s3v[r] + pre[r] + x[idx];
            out[idx] = fmaxf(y, 0.f);
        }
    }
}

extern "C" void kernel_launch(void* const* d_in, const int* in_sizes, int n_in,
                              void* d_out, int out_size, void* d_ws, size_t ws_size,
                              hipStream_t stream) {
    const float* x       = (const float*)d_in[0];
    const float* A       = (const float*)d_in[1];
    const float* bn1_g   = (const float*)d_in[2];
    const float* bn1_b   = (const float*)d_in[3];
    const float* bn1_m   = (const float*)d_in[4];
    const float* bn1_v   = (const float*)d_in[5];
    const float* pconv_w = (const float*)d_in[6];
    const float* pconv_b = (const float*)d_in[7];
    const float* wq      = (const float*)d_in[8];
    const float* wk      = (const float*)d_in[9];
    const float* wv      = (const float*)d_in[10];
    const float* fc_w    = (const float*)d_in[11];
    const float* ln_g    = (const float*)d_in[12];
    const float* ln_b    = (const float*)d_in[13];
    const float* gate_w  = (const float*)d_in[14];
    const float* bn2_g   = (const float*)d_in[15];
    const float* bn2_b   = (const float*)d_in[16];
    const float* bn2_m   = (const float*)d_in[17];
    const float* bn2_v   = (const float*)d_in[18];
    const float* tconv_w = (const float*)d_in[19];
    const float* tconv_b = (const float*)d_in[20];
    const float* bn3_g   = (const float*)d_in[21];
    const float* bn3_b   = (const float*)d_in[22];
    const float* bn3_m   = (const float*)d_in[23];
    const float* bn3_v   = (const float*)d_in[24];

    char* ws = (char*)d_ws;
    u16*   f_bf  = (u16*)ws;
    u16*   akt   = (u16*)(ws + WOFF);
    u16*   wp2   = (u16*)(ws + WOFF + 7680);
    u16*   wqt   = (u16*)(ws + WOFF + 32256);
    u16*   wkt   = (u16*)(ws + WOFF + 40448);
    u16*   wvt   = (u16*)(ws + WOFF + 48640);
    u16*   fct   = (u16*)(ws + WOFF + 56832);
    float* bagg  = (float*)(ws + WOFF + 65024);
    u16*   wtc   = (u16*)(ws + WOFF + 71424);
    float* uvec  = (float*)(ws + WOFF + 145152);
    float* w0vec = (float*)(ws + WOFF + 145408);
    float* bnc   = (float*)(ws + WOFF + 145664);
    float* outp  = (float*)d_out;

    prep_kernel<<<dim3(64), dim3(256), 0, stream>>>(
        A, pconv_w, pconv_b, wq, wk, wv, fc_w, tconv_w, tconv_b, ln_g, ln_b,
        bn1_g, bn1_b, bn1_m, bn1_v, bn2_g, bn2_b, bn2_m, bn2_v,
        bn3_g, bn3_b, bn3_m, bn3_v,
        akt, wp2, wqt, wkt, wvt, fct, bagg, wtc, uvec, w0vec, bnc);
    scn_kernel<<<dim3(NB * T), dim3(256), 0, stream>>>(
        x, akt, wp2, wqt, wkt, wvt, fct, bagg, uvec, w0vec, gate_w, bnc, f_bf);
    tcn_mfma<<<dim3(NB * 32), dim3(256), 0, stream>>>(
        f_bf, x, wtc, bnc, outp);
}